// Round 8
// baseline (220.986 us; speedup 1.0000x reference)
//
#include <hip/hip_runtime.h>
#include <hip/hip_fp16.h>

// Problem constants: x (1,64,8,56,56), offset (1,648,8,56,56),
// weight (64,64,3,3,3), stride=1, pad=1, cpg=8.
namespace {
constexpr int D_ = 8, H_ = 56, W_ = 56;
constexpr int HW_ = H_ * W_;
constexpr int KV_ = 27;
constexpr int N_ = D_ * H_ * W_;    // 25088
constexpr int NT_ = 16;
constexpr int NTILES_ = N_ / NT_;   // 1568
}

typedef _Float16 f16x8 __attribute__((ext_vector_type(8)));
typedef float f32x4 __attribute__((ext_vector_type(4)));

union U4H { uint4 u; __half2 h[4]; f16x8 v; };

// prep: xt[g][n][8] f16  and  wt2[kv][of][ks][lane][8] f16
__global__ __launch_bounds__(256) void prep_kernel(const float* __restrict__ x,
                                                   const float* __restrict__ w,
                                                   __half* __restrict__ xt,
                                                   __half* __restrict__ wt2) {
    const int b = blockIdx.x, tid = threadIdx.x;
    if (b < 784) {
        const int g = b / 98;
        const int n = (b % 98) * 256 + tid;
        U4H p;
#pragma unroll
        for (int cc = 0; cc < 4; ++cc) {
            float lo = x[(size_t)(g * 8 + 2 * cc) * N_ + n];
            float hi = x[(size_t)(g * 8 + 2 * cc + 1) * N_ + n];
            p.h[cc] = __floats2half2_rn(lo, hi);
        }
        *(uint4*)(xt + ((size_t)g * N_ + n) * 8) = p.u;
    } else {
        const int idx = (b - 784) * 256 + tid;    // 0 .. 110591
        const int e  = idx & 7;
        const int l  = (idx >> 3) & 63;
        const int ks = (idx >> 9) & 1;
        const int of = (idx >> 10) & 3;
        const int kv = idx >> 12;                 // 0..26
        const int o = of * 16 + (l & 15);
        const int c = ks * 32 + (l >> 4) * 8 + e;
        wt2[idx] = __float2half(w[(size_t)(o * 64 + c) * 27 + kv]);
    }
}

#define CORN(DU, WF, A) do {                                                   \
    U4H d_; d_.u = (DU);                                                       \
    __half2 w2_ = __float2half2_rn(WF);                                        \
    A.h[0] = __hfma2(d_.h[0], w2_, A.h[0]);                                    \
    A.h[1] = __hfma2(d_.h[1], w2_, A.h[1]);                                    \
    A.h[2] = __hfma2(d_.h[2], w2_, A.h[2]);                                    \
    A.h[3] = __hfma2(d_.h[3], w2_, A.h[3]);                                    \
} while (0)

// ---------- decoupled path ----------
// One thread per (kv,g,n) sample. Output layout = MFMA B-fragment blocks:
// val[kvi][nt][g][nl][8ch] f16, so GEMM B-loads are single-segment 1KB wave loads.
__global__ __launch_bounds__(256, 6) void gather_kernel(const float* __restrict__ offset,
                                                        const __half* __restrict__ xt,
                                                        __half* __restrict__ val,
                                                        int kv0) {
    const int bid = blockIdx.x;
    const int kvi = bid / 784;                 // 0..8
    const int kv = kv0 + kvi;
    const int g = (bid / 98) % 8;
    const int n = (bid % 98) * 256 + threadIdx.x;
    const int kz = kv / 9, ky = (kv / 3) % 3, kx = kv % 3;
    const int zo = n / HW_;
    const int rem = n - zo * HW_;
    const int yo = rem / W_;
    const int xo = rem - yo * W_;

    const float* p = offset + ((size_t)(g * KV_ + kv) * 3) * N_ + n;
    const float oz = __builtin_nontemporal_load(p);
    const float oy = __builtin_nontemporal_load(p + N_);
    const float ox = __builtin_nontemporal_load(p + 2 * N_);

    float zc = (float)(zo + kz - 1) + oz;
    float yc = (float)(yo + ky - 1) + oy;
    float xc = (float)(xo + kx - 1) + ox;
    float zf = floorf(zc), yf = floorf(yc), xf = floorf(xc);
    float dz = zc - zf, dy = yc - yf, dx = xc - xf;
    int z0 = (int)zf, y0 = (int)yf, x0 = (int)xf;
    int z1 = z0 + 1, y1 = y0 + 1, x1 = x0 + 1;
    float wz0 = (1.f - dz) * ((unsigned)z0 < (unsigned)D_ ? 1.f : 0.f);
    float wz1 = dz * ((unsigned)z1 < (unsigned)D_ ? 1.f : 0.f);
    float wy0 = (1.f - dy) * ((unsigned)y0 < (unsigned)H_ ? 1.f : 0.f);
    float wy1 = dy * ((unsigned)y1 < (unsigned)H_ ? 1.f : 0.f);
    float wx0 = (1.f - dx) * ((unsigned)x0 < (unsigned)W_ ? 1.f : 0.f);
    float wx1 = dx * ((unsigned)x1 < (unsigned)W_ ? 1.f : 0.f);
    int z0c = min(max(z0, 0), D_ - 1), z1c = min(max(z1, 0), D_ - 1);
    int y0c = min(max(y0, 0), H_ - 1), y1c = min(max(y1, 0), H_ - 1);
    int x0c = min(max(x0, 0), W_ - 1), x1c = min(max(x1, 0), W_ - 1);
    const uint4* xp = (const uint4*)(xt + (size_t)g * (N_ * 8));
    int zy00 = z0c * HW_ + y0c * W_, zy01 = z0c * HW_ + y1c * W_;
    int zy10 = z1c * HW_ + y0c * W_, zy11 = z1c * HW_ + y1c * W_;

    // 8 independent gathers in flight
    uint4 c0 = xp[zy00 + x0c], c1 = xp[zy00 + x1c];
    uint4 c2 = xp[zy01 + x0c], c3 = xp[zy01 + x1c];
    uint4 c4 = xp[zy10 + x0c], c5 = xp[zy10 + x1c];
    uint4 c6 = xp[zy11 + x0c], c7 = xp[zy11 + x1c];

    U4H a0, a1;
    a0.u = make_uint4(0u, 0u, 0u, 0u);
    a1.u = make_uint4(0u, 0u, 0u, 0u);
    float wzy00 = wz0 * wy0, wzy01 = wz0 * wy1;
    float wzy10 = wz1 * wy0, wzy11 = wz1 * wy1;
    CORN(c0, wzy00 * wx0, a0); CORN(c1, wzy00 * wx1, a1);
    CORN(c2, wzy01 * wx0, a0); CORN(c3, wzy01 * wx1, a1);
    CORN(c4, wzy10 * wx0, a0); CORN(c5, wzy10 * wx1, a1);
    CORN(c6, wzy11 * wx0, a0); CORN(c7, wzy11 * wx1, a1);
    a0.h[0] = __hadd2(a0.h[0], a1.h[0]);
    a0.h[1] = __hadd2(a0.h[1], a1.h[1]);
    a0.h[2] = __hadd2(a0.h[2], a1.h[2]);
    a0.h[3] = __hadd2(a0.h[3], a1.h[3]);

    const size_t didx = ((size_t)(kvi * NTILES_ + (n >> 4)) * 1024) + g * 128 + (n & 15) * 8;
    *(uint4*)(val + didx) = a0.u;
}

// GEMM over one 9-tap chunk: out[o][n] (+)= sum_kvi w[o][c]*val[c][n]
__global__ __launch_bounds__(256, 4) void gemm_kernel(const __half* __restrict__ val,
                                                      const __half* __restrict__ wt2,
                                                      float* __restrict__ out,
                                                      int kv0, int accum) {
    const int tid = threadIdx.x, lane = tid & 63, wv = tid >> 6;
    const int nt = blockIdx.x * 4 + wv;        // 0..1567
    const int n0 = nt * NT_, nl = lane & 15;
    f32x4 acc[4] = {};
    const __half* vb = val + (size_t)nt * 1024 + lane * 8;
    const __half* wb0 = wt2 + (size_t)kv0 * 4096 + lane * 8;
#pragma unroll
    for (int kvi = 0; kvi < 9; ++kvi) {
        const __half* vp = vb + (size_t)kvi * (NTILES_ * 1024);
        f16x8 bf0 = *(const f16x8*)(vp);
        f16x8 bf1 = *(const f16x8*)(vp + 512);
        const __half* wb = wb0 + kvi * 4096;
        f16x8 a00 = *(const f16x8*)(wb);
        f16x8 a01 = *(const f16x8*)(wb + 1024);
        f16x8 a02 = *(const f16x8*)(wb + 2048);
        f16x8 a03 = *(const f16x8*)(wb + 3072);
        acc[0] = __builtin_amdgcn_mfma_f32_16x16x32_f16(a00, bf0, acc[0], 0, 0, 0);
        acc[1] = __builtin_amdgcn_mfma_f32_16x16x32_f16(a01, bf0, acc[1], 0, 0, 0);
        acc[2] = __builtin_amdgcn_mfma_f32_16x16x32_f16(a02, bf0, acc[2], 0, 0, 0);
        acc[3] = __builtin_amdgcn_mfma_f32_16x16x32_f16(a03, bf0, acc[3], 0, 0, 0);
        f16x8 a10 = *(const f16x8*)(wb + 512);
        f16x8 a11 = *(const f16x8*)(wb + 1536);
        f16x8 a12 = *(const f16x8*)(wb + 2560);
        f16x8 a13 = *(const f16x8*)(wb + 3584);
        acc[0] = __builtin_amdgcn_mfma_f32_16x16x32_f16(a10, bf1, acc[0], 0, 0, 0);
        acc[1] = __builtin_amdgcn_mfma_f32_16x16x32_f16(a11, bf1, acc[1], 0, 0, 0);
        acc[2] = __builtin_amdgcn_mfma_f32_16x16x32_f16(a12, bf1, acc[2], 0, 0, 0);
        acc[3] = __builtin_amdgcn_mfma_f32_16x16x32_f16(a13, bf1, acc[3], 0, 0, 0);
    }
#pragma unroll
    for (int of = 0; of < 4; ++of)
#pragma unroll
        for (int r = 0; r < 4; ++r) {
            float* dp = out + (size_t)(of * 16 + (lane >> 4) * 4 + r) * N_ + n0 + nl;
            if (accum) *dp = *dp + acc[of][r]; else *dp = acc[of][r];
        }
}

// ---------- fused fallback (R7) ----------
#define ISSUE(PH, KY, KX, OZ, OY, OX, BUF, WW) do {                            \
    float zc = (float)(zo + kz - 1) + (OZ);                                    \
    float yc = (float)(yo + (KY) - 1) + (OY);                                  \
    float xc = (float)(xo + (KX) - 1) + (OX);                                  \
    float zf = floorf(zc), yf = floorf(yc), xf = floorf(xc);                   \
    float dz = zc - zf, dy = yc - yf, dx = xc - xf;                            \
    int z0 = (int)zf, y0 = (int)yf, x0 = (int)xf;                              \
    int z1 = z0 + 1, y1 = y0 + 1, x1 = x0 + 1;                                 \
    WW[0] = (1.f - dz) * ((unsigned)z0 < (unsigned)D_ ? 1.f : 0.f);            \
    WW[1] = dz * ((unsigned)z1 < (unsigned)D_ ? 1.f : 0.f);                    \
    WW[2] = (1.f - dy) * ((unsigned)y0 < (unsigned)H_ ? 1.f : 0.f);            \
    WW[3] = dy * ((unsigned)y1 < (unsigned)H_ ? 1.f : 0.f);                    \
    WW[4] = (1.f - dx) * ((unsigned)x0 < (unsigned)W_ ? 1.f : 0.f);            \
    WW[5] = dx * ((unsigned)x1 < (unsigned)W_ ? 1.f : 0.f);                    \
    int z0c = min(max(z0, 0), D_ - 1), z1c = min(max(z1, 0), D_ - 1);          \
    int y0c = min(max(y0, 0), H_ - 1), y1c = min(max(y1, 0), H_ - 1);          \
    int x0c = min(max(x0, 0), W_ - 1), x1c = min(max(x1, 0), W_ - 1);          \
    const uint4* xp_ = xg[PH];                                                 \
    int zy00 = z0c * HW_ + y0c * W_, zy01 = z0c * HW_ + y1c * W_;              \
    int zy10 = z1c * HW_ + y0c * W_, zy11 = z1c * HW_ + y1c * W_;              \
    BUF[0] = xp_[zy00 + x0c]; BUF[1] = xp_[zy00 + x1c];                        \
    BUF[2] = xp_[zy01 + x0c]; BUF[3] = xp_[zy01 + x1c];                        \
    BUF[4] = xp_[zy10 + x0c]; BUF[5] = xp_[zy10 + x1c];                        \
    BUF[6] = xp_[zy11 + x0c]; BUF[7] = xp_[zy11 + x1c];                        \
} while (0)

#define CONSUME(BUF, WW, BF) do {                                              \
    U4H a0_, a1_;                                                              \
    a0_.u = make_uint4(0u, 0u, 0u, 0u);                                        \
    a1_.u = make_uint4(0u, 0u, 0u, 0u);                                        \
    float wzy00 = WW[0] * WW[2], wzy01 = WW[0] * WW[3];                        \
    float wzy10 = WW[1] * WW[2], wzy11 = WW[1] * WW[3];                        \
    CORN(BUF[0], wzy00 * WW[4], a0_); CORN(BUF[1], wzy00 * WW[5], a1_);        \
    CORN(BUF[2], wzy01 * WW[4], a0_); CORN(BUF[3], wzy01 * WW[5], a1_);        \
    CORN(BUF[4], wzy10 * WW[4], a0_); CORN(BUF[5], wzy10 * WW[5], a1_);        \
    CORN(BUF[6], wzy11 * WW[4], a0_); CORN(BUF[7], wzy11 * WW[5], a1_);        \
    a0_.h[0] = __hadd2(a0_.h[0], a1_.h[0]);                                    \
    a0_.h[1] = __hadd2(a0_.h[1], a1_.h[1]);                                    \
    a0_.h[2] = __hadd2(a0_.h[2], a1_.h[2]);                                    \
    a0_.h[3] = __hadd2(a0_.h[3], a1_.h[3]);                                    \
    BF = a0_.v;                                                                \
} while (0)

__global__ __launch_bounds__(192, 3) void dconv_kernel(const float* __restrict__ offset,
                                                       const __half* __restrict__ xt,
                                                       const __half* __restrict__ wt2,
                                                       float* __restrict__ out) {
    __shared__ float red_s[3][64][20];
    const int tid = threadIdx.x;
    const int lane = tid & 63;
    const int wv = tid >> 6;
    const int r = blockIdx.x;
    const int tile = (r & 7) * 196 + (r >> 3);
    const int n0 = tile * NT_;
    const int nl = lane & 15;
    const int n = n0 + nl;
    const int kv0 = wv * 9;
    const int kz = wv;

    const int zo = n / HW_;
    const int rem = n - zo * HW_;
    const int yo = rem / W_;
    const int xo = rem - yo * W_;
    const uint4* xg[2];
    const float* ob[2];
#pragma unroll
    for (int ph = 0; ph < 2; ++ph) {
        const int g = ph * 4 + (lane >> 4);
        xg[ph] = (const uint4*)(xt + (size_t)g * (N_ * 8));
        ob[ph] = offset + (size_t)g * (KV_ * 3 * N_) + n;
    }

    uint4 bufA[8], bufB[8];
    float wA[6], wB[6];
    f32x4 acc[4] = {};
    f16x8 bf0, bf1;

    float o0z[2], o0y[2], o0x[2], onz[2], ony[2], onx[2];
#pragma unroll
    for (int ph = 0; ph < 2; ++ph) {
        const float* p = ob[ph] + (size_t)kv0 * 3 * N_;
        o0z[ph] = __builtin_nontemporal_load(p);
        o0y[ph] = __builtin_nontemporal_load(p + N_);
        o0x[ph] = __builtin_nontemporal_load(p + 2 * N_);
    }
    ISSUE(0, 0, 0, o0z[0], o0y[0], o0x[0], bufA, wA);
    ISSUE(1, 0, 0, o0z[1], o0y[1], o0x[1], bufB, wB);
#pragma unroll
    for (int ph = 0; ph < 2; ++ph) {
        const float* p = ob[ph] + (size_t)(kv0 + 1) * 3 * N_;
        onz[ph] = __builtin_nontemporal_load(p);
        ony[ph] = __builtin_nontemporal_load(p + N_);
        onx[ph] = __builtin_nontemporal_load(p + 2 * N_);
    }

#pragma unroll
    for (int t = 0; t < 9; ++t) {
        const int kv = kv0 + t;
        const __half* wb = wt2 + (size_t)kv * 4096 + lane * 8;
        f16x8 af00 = *(const f16x8*)(wb);
        f16x8 af01 = *(const f16x8*)(wb + 1024);
        f16x8 af02 = *(const f16x8*)(wb + 2048);
        f16x8 af03 = *(const f16x8*)(wb + 3072);
        CONSUME(bufA, wA, bf0);
        if (t < 8)
            ISSUE(0, (t + 1) / 3, (t + 1) % 3, onz[0], ony[0], onx[0], bufA, wA);
        __builtin_amdgcn_s_setprio(1);
        acc[0] = __builtin_amdgcn_mfma_f32_16x16x32_f16(af00, bf0, acc[0], 0, 0, 0);
        acc[1] = __builtin_amdgcn_mfma_f32_16x16x32_f16(af01, bf0, acc[1], 0, 0, 0);
        acc[2] = __builtin_amdgcn_mfma_f32_16x16x32_f16(af02, bf0, acc[2], 0, 0, 0);
        acc[3] = __builtin_amdgcn_mfma_f32_16x16x32_f16(af03, bf0, acc[3], 0, 0, 0);
        __builtin_amdgcn_s_setprio(0);
        f16x8 af10 = *(const f16x8*)(wb + 512);
        f16x8 af11 = *(const f16x8*)(wb + 1536);
        f16x8 af12 = *(const f16x8*)(wb + 2560);
        f16x8 af13 = *(const f16x8*)(wb + 3584);
        CONSUME(bufB, wB, bf1);
        if (t < 8)
            ISSUE(1, (t + 1) / 3, (t + 1) % 3, onz[1], ony[1], onx[1], bufB, wB);
        float tnz[2], tny[2], tnx[2];
        if (t < 7) {
#pragma unroll
            for (int ph = 0; ph < 2; ++ph) {
                const float* p = ob[ph] + (size_t)(kv + 2) * 3 * N_;
                tnz[ph] = __builtin_nontemporal_load(p);
                tny[ph] = __builtin_nontemporal_load(p + N_);
                tnx[ph] = __builtin_nontemporal_load(p + 2 * N_);
            }
        }
        __builtin_amdgcn_s_setprio(1);
        acc[0] = __builtin_amdgcn_mfma_f32_16x16x32_f16(af10, bf1, acc[0], 0, 0, 0);
        acc[1] = __builtin_amdgcn_mfma_f32_16x16x32_f16(af11, bf1, acc[1], 0, 0, 0);
        acc[2] = __builtin_amdgcn_mfma_f32_16x16x32_f16(af12, bf1, acc[2], 0, 0, 0);
        acc[3] = __builtin_amdgcn_mfma_f32_16x16x32_f16(af13, bf1, acc[3], 0, 0, 0);
        __builtin_amdgcn_s_setprio(0);
        if (t < 7) {
#pragma unroll
            for (int ph = 0; ph < 2; ++ph) {
                onz[ph] = tnz[ph]; ony[ph] = tny[ph]; onx[ph] = tnx[ph];
            }
        }
    }

#pragma unroll
    for (int of = 0; of < 4; ++of)
#pragma unroll
        for (int rr = 0; rr < 4; ++rr)
            red_s[wv][of * 16 + (lane >> 4) * 4 + rr][nl] = acc[of][rr];
    __syncthreads();
    for (int e = tid; e < 256; e += 192) {
        const int o = e >> 2, n4 = (e & 3) * 4;
        f32x4 s = *(const f32x4*)&red_s[0][o][n4]
                + *(const f32x4*)&red_s[1][o][n4]
                + *(const f32x4*)&red_s[2][o][n4];
        *(f32x4*)(out + (size_t)o * N_ + n0 + n4) = s;
    }
}

extern "C" void kernel_launch(void* const* d_in, const int* in_sizes, int n_in,
                              void* d_out, int out_size, void* d_ws, size_t ws_size,
                              hipStream_t stream) {
    const float* x      = (const float*)d_in[0];
    const float* offset = (const float*)d_in[1];
    const float* weight = (const float*)d_in[2];
    float* out = (float*)d_out;

    __half* xt  = (__half*)d_ws;                 // 3,211,264 B
    __half* wt2 = xt + (size_t)8 * N_ * 8;       // 221,184 B
    const size_t base = 3432448;
    const size_t chunk_bytes = (size_t)9 * NTILES_ * 1024 * 2;  // 28,901,376 B

    prep_kernel<<<784 + 432, 256, 0, stream>>>(x, weight, xt, wt2);

    if (ws_size >= base + chunk_bytes) {
        __half* val = (__half*)((char*)d_ws + base);
        for (int c = 0; c < 3; ++c) {
            gather_kernel<<<9 * 784, 256, 0, stream>>>(offset, xt, val, c * 9);
            gemm_kernel<<<NTILES_ / 4, 256, 0, stream>>>(val, wt2, out, c * 9, c);
        }
    } else {
        dconv_kernel<<<NTILES_, 192, 0, stream>>>(offset, xt, wt2, out);
    }
}

// Round 9
// 173.506 us; speedup vs baseline: 1.2736x; 1.2736x over previous
//
#include <hip/hip_runtime.h>
#include <hip/hip_fp16.h>

// Problem constants: x (1,64,8,56,56), offset (1,648,8,56,56),
// weight (64,64,3,3,3), stride=1, pad=1, cpg=8.
namespace {
constexpr int D_ = 8, H_ = 56, W_ = 56;
constexpr int HW_ = H_ * W_;
constexpr int KV_ = 27;
constexpr int N_ = D_ * H_ * W_;    // 25088
constexpr int NT_ = 16;
constexpr int NTILES_ = N_ / NT_;   // 1568
}

typedef _Float16 f16x8 __attribute__((ext_vector_type(8)));
typedef float f32x4 __attribute__((ext_vector_type(4)));

union U4H { uint4 u; __half2 h[4]; f16x8 v; };

// prep: xt[g][n][8] f16  and  wt2[kv][of][ks][lane][8] f16
__global__ __launch_bounds__(256) void prep_kernel(const float* __restrict__ x,
                                                   const float* __restrict__ w,
                                                   __half* __restrict__ xt,
                                                   __half* __restrict__ wt2) {
    const int b = blockIdx.x, tid = threadIdx.x;
    if (b < 784) {
        const int g = b / 98;
        const int n = (b % 98) * 256 + tid;
        U4H p;
#pragma unroll
        for (int cc = 0; cc < 4; ++cc) {
            float lo = x[(size_t)(g * 8 + 2 * cc) * N_ + n];
            float hi = x[(size_t)(g * 8 + 2 * cc + 1) * N_ + n];
            p.h[cc] = __floats2half2_rn(lo, hi);
        }
        *(uint4*)(xt + ((size_t)g * N_ + n) * 8) = p.u;
    } else {
        const int idx = (b - 784) * 256 + tid;    // 0 .. 110591
        const int e  = idx & 7;
        const int l  = (idx >> 3) & 63;
        const int ks = (idx >> 9) & 1;
        const int of = (idx >> 10) & 3;
        const int kv = idx >> 12;                 // 0..26
        const int o = of * 16 + (l & 15);
        const int c = ks * 32 + (l >> 4) * 8 + e;
        wt2[idx] = __float2half(w[(size_t)(o * 64 + c) * 27 + kv]);
    }
}

#define CORN(DU, WF, A) do {                                                   \
    U4H d_; d_.u = (DU);                                                       \
    __half2 w2_ = __float2half2_rn(WF);                                        \
    A.h[0] = __hfma2(d_.h[0], w2_, A.h[0]);                                    \
    A.h[1] = __hfma2(d_.h[1], w2_, A.h[1]);                                    \
    A.h[2] = __hfma2(d_.h[2], w2_, A.h[2]);                                    \
    A.h[3] = __hfma2(d_.h[3], w2_, A.h[3]);                                    \
} while (0)

// ---------- LDS-staged gather ----------
// Block = (g, y-pair, kz-plane). Stage window [8z][<=10y][56x][8ch] (70KB LDS);
// x and z are FULLY staged, so clamped coords always hit; only y can fall
// outside (offset |dy|>~3, P~0.3%) -> per-lane global fallback.
// Output layout = MFMA B-fragment blocks: val[kv][nt][g][nl][8ch] f16.
__global__ __launch_bounds__(512, 4) void gather_kernel(const float* __restrict__ offset,
                                                        const __half* __restrict__ xt,
                                                        __half* __restrict__ val) {
    __shared__ uint4 lds_x[8 * 10 * 56];   // 71,680 B
    // XCD swizzle: each XCD's L2 keeps ~1 group's xt slice hot
    const int b2 = (blockIdx.x & 7) * 84 + (blockIdx.x >> 3);   // 672 = 8*84
    const int g = b2 / 84;
    const int r = b2 % 84;
    const int ys = (r / 3) * 2;            // 0,2,...,54
    const int kvt = r % 3;                 // kz plane
    const int tid = threadIdx.x;

    const int ylo = max(0, ys - 4);
    const int yhi = min(55, ys + 5);
    const int Yw = yhi - ylo + 1;          // 6..10

    const uint4* xs = (const uint4*)(xt + (size_t)g * (N_ * 8));

    // ---- stage the window (coalesced row copies) ----
    {
        const int tot = 8 * Yw * 56;
        for (int i = tid; i < tot; i += 512) {
            int z = i / (Yw * 56);
            int rem = i - z * (Yw * 56);
            int yy = rem / 56;
            int x = rem - yy * 56;
            lds_x[(z * 10 + yy) * 56 + x] = xs[z * HW_ + (ylo + yy) * 56 + x];
        }
    }
    __syncthreads();

    const float* obase = offset + (size_t)g * (KV_ * 3 * N_);
    const int kz = kvt;

    // samples: 9 taps x (2y * 56x * 8z = 896 positions) = 8064
    for (int s = tid; s < 8064; s += 512) {
        const int kvi = s / 896;
        const int p = s - kvi * 896;
        const int z = p / 112;
        const int rem = p - z * 112;
        const int yrow = rem / 56;
        const int x = rem - yrow * 56;
        const int y = ys + yrow;
        const int n = z * HW_ + y * W_ + x;
        const int kv = kvt * 9 + kvi;
        const int ky = kvi / 3, kx = kvi - ky * 3;

        const float* pofs = obase + (size_t)(kv * 3) * N_ + n;
        const float oz = __builtin_nontemporal_load(pofs);
        const float oy = __builtin_nontemporal_load(pofs + N_);
        const float ox = __builtin_nontemporal_load(pofs + 2 * N_);

        float zc = (float)(z + kz - 1) + oz;
        float yc = (float)(y + ky - 1) + oy;
        float xc = (float)(x + kx - 1) + ox;
        float zf = floorf(zc), yf = floorf(yc), xf = floorf(xc);
        float dz = zc - zf, dy = yc - yf, dx = xc - xf;
        int z0 = (int)zf, y0 = (int)yf, x0 = (int)xf;
        int z1 = z0 + 1, y1 = y0 + 1, x1 = x0 + 1;
        float wz0 = (1.f - dz) * ((unsigned)z0 < (unsigned)D_ ? 1.f : 0.f);
        float wz1 = dz * ((unsigned)z1 < (unsigned)D_ ? 1.f : 0.f);
        float wy0 = (1.f - dy) * ((unsigned)y0 < (unsigned)H_ ? 1.f : 0.f);
        float wy1 = dy * ((unsigned)y1 < (unsigned)H_ ? 1.f : 0.f);
        float wx0 = (1.f - dx) * ((unsigned)x0 < (unsigned)W_ ? 1.f : 0.f);
        float wx1 = dx * ((unsigned)x1 < (unsigned)W_ ? 1.f : 0.f);
        int z0c = min(max(z0, 0), D_ - 1), z1c = min(max(z1, 0), D_ - 1);
        int y0c = min(max(y0, 0), H_ - 1), y1c = min(max(y1, 0), H_ - 1);
        int x0c = min(max(x0, 0), W_ - 1), x1c = min(max(x1, 0), W_ - 1);

        uint4 c0, c1, c2, c3, c4, c5, c6, c7;
        const bool inw = (y0c >= ylo) && (y1c <= yhi);
        if (inw) {
            const int r00 = (z0c * 10 + (y0c - ylo)) * 56;
            const int r01 = (z0c * 10 + (y1c - ylo)) * 56;
            const int r10 = (z1c * 10 + (y0c - ylo)) * 56;
            const int r11 = (z1c * 10 + (y1c - ylo)) * 56;
            c0 = lds_x[r00 + x0c]; c1 = lds_x[r00 + x1c];
            c2 = lds_x[r01 + x0c]; c3 = lds_x[r01 + x1c];
            c4 = lds_x[r10 + x0c]; c5 = lds_x[r10 + x1c];
            c6 = lds_x[r11 + x0c]; c7 = lds_x[r11 + x1c];
        } else {
            const int zy00 = z0c * HW_ + y0c * W_, zy01 = z0c * HW_ + y1c * W_;
            const int zy10 = z1c * HW_ + y0c * W_, zy11 = z1c * HW_ + y1c * W_;
            c0 = xs[zy00 + x0c]; c1 = xs[zy00 + x1c];
            c2 = xs[zy01 + x0c]; c3 = xs[zy01 + x1c];
            c4 = xs[zy10 + x0c]; c5 = xs[zy10 + x1c];
            c6 = xs[zy11 + x0c]; c7 = xs[zy11 + x1c];
        }

        U4H a0, a1;
        a0.u = make_uint4(0u, 0u, 0u, 0u);
        a1.u = make_uint4(0u, 0u, 0u, 0u);
        float wzy00 = wz0 * wy0, wzy01 = wz0 * wy1;
        float wzy10 = wz1 * wy0, wzy11 = wz1 * wy1;
        CORN(c0, wzy00 * wx0, a0); CORN(c1, wzy00 * wx1, a1);
        CORN(c2, wzy01 * wx0, a0); CORN(c3, wzy01 * wx1, a1);
        CORN(c4, wzy10 * wx0, a0); CORN(c5, wzy10 * wx1, a1);
        CORN(c6, wzy11 * wx0, a0); CORN(c7, wzy11 * wx1, a1);
        a0.h[0] = __hadd2(a0.h[0], a1.h[0]);
        a0.h[1] = __hadd2(a0.h[1], a1.h[1]);
        a0.h[2] = __hadd2(a0.h[2], a1.h[2]);
        a0.h[3] = __hadd2(a0.h[3], a1.h[3]);

        const size_t didx = ((size_t)(kv * NTILES_ + (n >> 4)) << 10) + g * 128 + (n & 15) * 8;
        *(uint4*)(val + didx) = a0.u;
    }
}

// Full-K GEMM: block = 1 n-tile, 4 waves split 27 taps (7/7/7/6), LDS-reduce.
__global__ __launch_bounds__(256, 4) void gemm_kernel(const __half* __restrict__ val,
                                                      const __half* __restrict__ wt2,
                                                      float* __restrict__ out) {
    __shared__ float red_s[4][64][20];
    const int tid = threadIdx.x, lane = tid & 63, wv = tid >> 6;
    const int nt = blockIdx.x;
    const int n0 = nt * NT_, nl = lane & 15;
    const int kv0 = wv * 7;
    f32x4 acc[4] = {};
    const __half* vb = val + (size_t)nt * 1024 + lane * 8;
    const __half* wb0 = wt2 + lane * 8;
#pragma unroll
    for (int t = 0; t < 7; ++t) {
        const int kv = kv0 + t;
        if (kv < KV_) {
            const __half* vp = vb + (size_t)kv * (NTILES_ * 1024);
            f16x8 bf0 = *(const f16x8*)(vp);
            f16x8 bf1 = *(const f16x8*)(vp + 512);
            const __half* wb = wb0 + (size_t)kv * 4096;
            f16x8 a00 = *(const f16x8*)(wb);
            f16x8 a01 = *(const f16x8*)(wb + 1024);
            f16x8 a02 = *(const f16x8*)(wb + 2048);
            f16x8 a03 = *(const f16x8*)(wb + 3072);
            acc[0] = __builtin_amdgcn_mfma_f32_16x16x32_f16(a00, bf0, acc[0], 0, 0, 0);
            acc[1] = __builtin_amdgcn_mfma_f32_16x16x32_f16(a01, bf0, acc[1], 0, 0, 0);
            acc[2] = __builtin_amdgcn_mfma_f32_16x16x32_f16(a02, bf0, acc[2], 0, 0, 0);
            acc[3] = __builtin_amdgcn_mfma_f32_16x16x32_f16(a03, bf0, acc[3], 0, 0, 0);
            f16x8 a10 = *(const f16x8*)(wb + 512);
            f16x8 a11 = *(const f16x8*)(wb + 1536);
            f16x8 a12 = *(const f16x8*)(wb + 2560);
            f16x8 a13 = *(const f16x8*)(wb + 3584);
            acc[0] = __builtin_amdgcn_mfma_f32_16x16x32_f16(a10, bf1, acc[0], 0, 0, 0);
            acc[1] = __builtin_amdgcn_mfma_f32_16x16x32_f16(a11, bf1, acc[1], 0, 0, 0);
            acc[2] = __builtin_amdgcn_mfma_f32_16x16x32_f16(a12, bf1, acc[2], 0, 0, 0);
            acc[3] = __builtin_amdgcn_mfma_f32_16x16x32_f16(a13, bf1, acc[3], 0, 0, 0);
        }
    }
#pragma unroll
    for (int of = 0; of < 4; ++of)
#pragma unroll
        for (int rr = 0; rr < 4; ++rr)
            red_s[wv][of * 16 + (lane >> 4) * 4 + rr][nl] = acc[of][rr];
    __syncthreads();
    const int o = tid >> 2, n4 = (tid & 3) * 4;
    f32x4 s = *(const f32x4*)&red_s[0][o][n4] + *(const f32x4*)&red_s[1][o][n4]
            + *(const f32x4*)&red_s[2][o][n4] + *(const f32x4*)&red_s[3][o][n4];
    *(f32x4*)(out + (size_t)o * N_ + n0 + n4) = s;
}

// ---------- fused fallback (R7, known-good) ----------
#define ISSUE(PH, KY, KX, OZ, OY, OX, BUF, WW) do {                            \
    float zc = (float)(zo + kz - 1) + (OZ);                                    \
    float yc = (float)(yo + (KY) - 1) + (OY);                                  \
    float xc = (float)(xo + (KX) - 1) + (OX);                                  \
    float zf = floorf(zc), yf = floorf(yc), xf = floorf(xc);                   \
    float dz = zc - zf, dy = yc - yf, dx = xc - xf;                            \
    int z0 = (int)zf, y0 = (int)yf, x0 = (int)xf;                              \
    int z1 = z0 + 1, y1 = y0 + 1, x1 = x0 + 1;                                 \
    WW[0] = (1.f - dz) * ((unsigned)z0 < (unsigned)D_ ? 1.f : 0.f);            \
    WW[1] = dz * ((unsigned)z1 < (unsigned)D_ ? 1.f : 0.f);                    \
    WW[2] = (1.f - dy) * ((unsigned)y0 < (unsigned)H_ ? 1.f : 0.f);            \
    WW[3] = dy * ((unsigned)y1 < (unsigned)H_ ? 1.f : 0.f);                    \
    WW[4] = (1.f - dx) * ((unsigned)x0 < (unsigned)W_ ? 1.f : 0.f);            \
    WW[5] = dx * ((unsigned)x1 < (unsigned)W_ ? 1.f : 0.f);                    \
    int z0c = min(max(z0, 0), D_ - 1), z1c = min(max(z1, 0), D_ - 1);          \
    int y0c = min(max(y0, 0), H_ - 1), y1c = min(max(y1, 0), H_ - 1);          \
    int x0c = min(max(x0, 0), W_ - 1), x1c = min(max(x1, 0), W_ - 1);          \
    const uint4* xp_ = xg[PH];                                                 \
    int zy00 = z0c * HW_ + y0c * W_, zy01 = z0c * HW_ + y1c * W_;              \
    int zy10 = z1c * HW_ + y0c * W_, zy11 = z1c * HW_ + y1c * W_;              \
    BUF[0] = xp_[zy00 + x0c]; BUF[1] = xp_[zy00 + x1c];                        \
    BUF[2] = xp_[zy01 + x0c]; BUF[3] = xp_[zy01 + x1c];                        \
    BUF[4] = xp_[zy10 + x0c]; BUF[5] = xp_[zy10 + x1c];                        \
    BUF[6] = xp_[zy11 + x0c]; BUF[7] = xp_[zy11 + x1c];                        \
} while (0)

#define CONSUME(BUF, WW, BF) do {                                              \
    U4H a0_, a1_;                                                              \
    a0_.u = make_uint4(0u, 0u, 0u, 0u);                                        \
    a1_.u = make_uint4(0u, 0u, 0u, 0u);                                        \
    float wzy00 = WW[0] * WW[2], wzy01 = WW[0] * WW[3];                        \
    float wzy10 = WW[1] * WW[2], wzy11 = WW[1] * WW[3];                        \
    CORN(BUF[0], wzy00 * WW[4], a0_); CORN(BUF[1], wzy00 * WW[5], a1_);        \
    CORN(BUF[2], wzy01 * WW[4], a0_); CORN(BUF[3], wzy01 * WW[5], a1_);        \
    CORN(BUF[4], wzy10 * WW[4], a0_); CORN(BUF[5], wzy10 * WW[5], a1_);        \
    CORN(BUF[6], wzy11 * WW[4], a0_); CORN(BUF[7], wzy11 * WW[5], a1_);        \
    a0_.h[0] = __hadd2(a0_.h[0], a1_.h[0]);                                    \
    a0_.h[1] = __hadd2(a0_.h[1], a1_.h[1]);                                    \
    a0_.h[2] = __hadd2(a0_.h[2], a1_.h[2]);                                    \
    a0_.h[3] = __hadd2(a0_.h[3], a1_.h[3]);                                    \
    BF = a0_.v;                                                                \
} while (0)

__global__ __launch_bounds__(192, 3) void dconv_kernel(const float* __restrict__ offset,
                                                       const __half* __restrict__ xt,
                                                       const __half* __restrict__ wt2,
                                                       float* __restrict__ out) {
    __shared__ float red_s[3][64][20];
    const int tid = threadIdx.x;
    const int lane = tid & 63;
    const int wv = tid >> 6;
    const int r = blockIdx.x;
    const int tile = (r & 7) * 196 + (r >> 3);
    const int n0 = tile * NT_;
    const int nl = lane & 15;
    const int n = n0 + nl;
    const int kv0 = wv * 9;
    const int kz = wv;

    const int zo = n / HW_;
    const int rem = n - zo * HW_;
    const int yo = rem / W_;
    const int xo = rem - yo * W_;
    const uint4* xg[2];
    const float* ob[2];
#pragma unroll
    for (int ph = 0; ph < 2; ++ph) {
        const int g = ph * 4 + (lane >> 4);
        xg[ph] = (const uint4*)(xt + (size_t)g * (N_ * 8));
        ob[ph] = offset + (size_t)g * (KV_ * 3 * N_) + n;
    }

    uint4 bufA[8], bufB[8];
    float wA[6], wB[6];
    f32x4 acc[4] = {};
    f16x8 bf0, bf1;

    float o0z[2], o0y[2], o0x[2], onz[2], ony[2], onx[2];
#pragma unroll
    for (int ph = 0; ph < 2; ++ph) {
        const float* p = ob[ph] + (size_t)kv0 * 3 * N_;
        o0z[ph] = __builtin_nontemporal_load(p);
        o0y[ph] = __builtin_nontemporal_load(p + N_);
        o0x[ph] = __builtin_nontemporal_load(p + 2 * N_);
    }
    ISSUE(0, 0, 0, o0z[0], o0y[0], o0x[0], bufA, wA);
    ISSUE(1, 0, 0, o0z[1], o0y[1], o0x[1], bufB, wB);
#pragma unroll
    for (int ph = 0; ph < 2; ++ph) {
        const float* p = ob[ph] + (size_t)(kv0 + 1) * 3 * N_;
        onz[ph] = __builtin_nontemporal_load(p);
        ony[ph] = __builtin_nontemporal_load(p + N_);
        onx[ph] = __builtin_nontemporal_load(p + 2 * N_);
    }

#pragma unroll
    for (int t = 0; t < 9; ++t) {
        const int kv = kv0 + t;
        const __half* wb = wt2 + (size_t)kv * 4096 + lane * 8;
        f16x8 af00 = *(const f16x8*)(wb);
        f16x8 af01 = *(const f16x8*)(wb + 1024);
        f16x8 af02 = *(const f16x8*)(wb + 2048);
        f16x8 af03 = *(const f16x8*)(wb + 3072);
        CONSUME(bufA, wA, bf0);
        if (t < 8)
            ISSUE(0, (t + 1) / 3, (t + 1) % 3, onz[0], ony[0], onx[0], bufA, wA);
        __builtin_amdgcn_s_setprio(1);
        acc[0] = __builtin_amdgcn_mfma_f32_16x16x32_f16(af00, bf0, acc[0], 0, 0, 0);
        acc[1] = __builtin_amdgcn_mfma_f32_16x16x32_f16(af01, bf0, acc[1], 0, 0, 0);
        acc[2] = __builtin_amdgcn_mfma_f32_16x16x32_f16(af02, bf0, acc[2], 0, 0, 0);
        acc[3] = __builtin_amdgcn_mfma_f32_16x16x32_f16(af03, bf0, acc[3], 0, 0, 0);
        __builtin_amdgcn_s_setprio(0);
        f16x8 af10 = *(const f16x8*)(wb + 512);
        f16x8 af11 = *(const f16x8*)(wb + 1536);
        f16x8 af12 = *(const f16x8*)(wb + 2560);
        f16x8 af13 = *(const f16x8*)(wb + 3584);
        CONSUME(bufB, wB, bf1);
        if (t < 8)
            ISSUE(1, (t + 1) / 3, (t + 1) % 3, onz[1], ony[1], onx[1], bufB, wB);
        float tnz[2], tny[2], tnx[2];
        if (t < 7) {
#pragma unroll
            for (int ph = 0; ph < 2; ++ph) {
                const float* p = ob[ph] + (size_t)(kv + 2) * 3 * N_;
                tnz[ph] = __builtin_nontemporal_load(p);
                tny[ph] = __builtin_nontemporal_load(p + N_);
                tnx[ph] = __builtin_nontemporal_load(p + 2 * N_);
            }
        }
        __builtin_amdgcn_s_setprio(1);
        acc[0] = __builtin_amdgcn_mfma_f32_16x16x32_f16(af10, bf1, acc[0], 0, 0, 0);
        acc[1] = __builtin_amdgcn_mfma_f32_16x16x32_f16(af11, bf1, acc[1], 0, 0, 0);
        acc[2] = __builtin_amdgcn_mfma_f32_16x16x32_f16(af12, bf1, acc[2], 0, 0, 0);
        acc[3] = __builtin_amdgcn_mfma_f32_16x16x32_f16(af13, bf1, acc[3], 0, 0, 0);
        __builtin_amdgcn_s_setprio(0);
        if (t < 7) {
#pragma unroll
            for (int ph = 0; ph < 2; ++ph) {
                onz[ph] = tnz[ph]; ony[ph] = tny[ph]; onx[ph] = tnx[ph];
            }
        }
    }

#pragma unroll
    for (int of = 0; of < 4; ++of)
#pragma unroll
        for (int rr = 0; rr < 4; ++rr)
            red_s[wv][of * 16 + (lane >> 4) * 4 + rr][nl] = acc[of][rr];
    __syncthreads();
    for (int e = tid; e < 256; e += 192) {
        const int o = e >> 2, n4 = (e & 3) * 4;
        f32x4 s = *(const f32x4*)&red_s[0][o][n4]
                + *(const f32x4*)&red_s[1][o][n4]
                + *(const f32x4*)&red_s[2][o][n4];
        *(f32x4*)(out + (size_t)o * N_ + n0 + n4) = s;
    }
}

extern "C" void kernel_launch(void* const* d_in, const int* in_sizes, int n_in,
                              void* d_out, int out_size, void* d_ws, size_t ws_size,
                              hipStream_t stream) {
    const float* x      = (const float*)d_in[0];
    const float* offset = (const float*)d_in[1];
    const float* weight = (const float*)d_in[2];
    float* out = (float*)d_out;

    __half* xt  = (__half*)d_ws;                 // 3,211,264 B
    __half* wt2 = xt + (size_t)8 * N_ * 8;       // 221,184 B
    const size_t base = 3432448;
    const size_t val_bytes = (size_t)KV_ * NTILES_ * 1024 * 2;  // 86,704,128 B

    prep_kernel<<<784 + 432, 256, 0, stream>>>(x, weight, xt, wt2);

    if (ws_size >= base + val_bytes) {
        __half* val = (__half*)((char*)d_ws + base);
        gather_kernel<<<672, 512, 0, stream>>>(offset, xt, val);
        gemm_kernel<<<NTILES_, 256, 0, stream>>>(val, wt2, out);
    } else {
        dconv_kernel<<<NTILES_, 192, 0, stream>>>(offset, xt, wt2, out);
    }
}

// Round 10
// 171.519 us; speedup vs baseline: 1.2884x; 1.0116x over previous
//
#include <hip/hip_runtime.h>
#include <hip/hip_fp16.h>

// Problem constants: x (1,64,8,56,56), offset (1,648,8,56,56),
// weight (64,64,3,3,3), stride=1, pad=1, cpg=8.
namespace {
constexpr int D_ = 8, H_ = 56, W_ = 56;
constexpr int HW_ = H_ * W_;
constexpr int KV_ = 27;
constexpr int N_ = D_ * H_ * W_;    // 25088
constexpr int NT_ = 16;
constexpr int NTILES_ = N_ / NT_;   // 1568
}

typedef _Float16 f16x8 __attribute__((ext_vector_type(8)));
typedef float f32x4 __attribute__((ext_vector_type(4)));

union U4H { uint4 u; __half2 h[4]; f16x8 v; };

// prep: xt[g][n][8] f16  and  wt2[kv][of][ks][lane][8] f16
__global__ __launch_bounds__(256) void prep_kernel(const float* __restrict__ x,
                                                   const float* __restrict__ w,
                                                   __half* __restrict__ xt,
                                                   __half* __restrict__ wt2) {
    const int b = blockIdx.x, tid = threadIdx.x;
    if (b < 784) {
        const int g = b / 98;
        const int n = (b % 98) * 256 + tid;
        U4H p;
#pragma unroll
        for (int cc = 0; cc < 4; ++cc) {
            float lo = x[(size_t)(g * 8 + 2 * cc) * N_ + n];
            float hi = x[(size_t)(g * 8 + 2 * cc + 1) * N_ + n];
            p.h[cc] = __floats2half2_rn(lo, hi);
        }
        *(uint4*)(xt + ((size_t)g * N_ + n) * 8) = p.u;
    } else {
        const int idx = (b - 784) * 256 + tid;    // 0 .. 110591
        const int e  = idx & 7;
        const int l  = (idx >> 3) & 63;
        const int ks = (idx >> 9) & 1;
        const int of = (idx >> 10) & 3;
        const int kv = idx >> 12;                 // 0..26
        const int o = of * 16 + (l & 15);
        const int c = ks * 32 + (l >> 4) * 8 + e;
        wt2[idx] = __float2half(w[(size_t)(o * 64 + c) * 27 + kv]);
    }
}

#define CORN(DU, WF, A) do {                                                   \
    U4H d_; d_.u = (DU);                                                       \
    __half2 w2_ = __float2half2_rn(WF);                                        \
    A.h[0] = __hfma2(d_.h[0], w2_, A.h[0]);                                    \
    A.h[1] = __hfma2(d_.h[1], w2_, A.h[1]);                                    \
    A.h[2] = __hfma2(d_.h[2], w2_, A.h[2]);                                    \
    A.h[3] = __hfma2(d_.h[3], w2_, A.h[3]);                                    \
} while (0)

// ---------- LDS-staged gather, x-split for 4 blocks/CU ----------
// Block = (g, y-pair, kz-plane, x-third). Window [8z][10y][<=28x][8ch] = 35.8KB.
// x,z margins staged; rare out-of-window (y or x) -> per-lane global fallback.
// Output layout = MFMA B-fragment blocks: val[kv][nt][g][nl][8ch] f16.
__global__ __launch_bounds__(512, 8) void gather_kernel(const float* __restrict__ offset,
                                                        const __half* __restrict__ xt,
                                                        __half* __restrict__ val) {
    __shared__ uint4 lds_x[8 * 10 * 28];   // 35,840 B
    const int bid = blockIdx.x;
    const int g = bid & 7;                 // XCD-pinned group
    const int r = bid >> 3;                // 0..251
    const int yp = r / 9;
    const int rr = r - yp * 9;
    const int kzp = rr / 3;                // kz plane
    const int xt3 = rr - kzp * 3;          // x third
    const int tid = threadIdx.x;

    const int ys = yp * 2;
    const int xbase = xt3 * 19;            // 0,19,38
    const int xw = (xt3 == 2) ? 18 : 19;
    const int xlo = max(0, xbase - 4);
    const int xhi = min(55, xbase + xw + 4);
    const int XW = xhi - xlo + 1;          // <= 28
    const int ylo = max(0, ys - 4);
    const int yhi = min(55, ys + 5);
    const int Yw = yhi - ylo + 1;          // 6..10

    const uint4* xs = (const uint4*)(xt + (size_t)g * (N_ * 8));

    // ---- stage window (coalesced row segments from L2) ----
    {
        const int tot = 8 * Yw * XW;
        for (int i = tid; i < tot; i += 512) {
            int z = i / (Yw * XW);
            int rem = i - z * (Yw * XW);
            int yy = rem / XW;
            int xx = rem - yy * XW;
            lds_x[(z * 10 + yy) * 28 + xx] = xs[z * HW_ + (ylo + yy) * W_ + (xlo + xx)];
        }
    }
    __syncthreads();

    const float* obase = offset + (size_t)g * (KV_ * 3 * N_);
    const int kz = kzp;
    const int tot_s = 9 * 8 * 2 * xw;      // 2736 or 2592

    for (int s = tid; s < tot_s; s += 512) {
        // s = ((kvi*8 + z)*2 + yrow)*xw + xi  (x innermost -> coalesced offsets)
        const int t1 = s / xw;
        const int xi = s - t1 * xw;
        const int yrow = t1 & 1;
        const int t2 = t1 >> 1;
        const int z = t2 & 7;
        const int kvi = t2 >> 3;
        const int x = xbase + xi;
        const int y = ys + yrow;
        const int n = z * HW_ + y * W_ + x;
        const int kv = kzp * 9 + kvi;
        const int ky = kvi / 3, kx = kvi - ky * 3;

        const float* pofs = obase + (size_t)(kv * 3) * N_ + n;
        const float oz = __builtin_nontemporal_load(pofs);
        const float oy = __builtin_nontemporal_load(pofs + N_);
        const float ox = __builtin_nontemporal_load(pofs + 2 * N_);

        float zc = (float)(z + kz - 1) + oz;
        float yc = (float)(y + ky - 1) + oy;
        float xc = (float)(x + kx - 1) + ox;
        float zf = floorf(zc), yf = floorf(yc), xf = floorf(xc);
        float dz = zc - zf, dy = yc - yf, dx = xc - xf;
        int z0 = (int)zf, y0 = (int)yf, x0 = (int)xf;
        int z1 = z0 + 1, y1 = y0 + 1, x1 = x0 + 1;
        float wz0 = (1.f - dz) * ((unsigned)z0 < (unsigned)D_ ? 1.f : 0.f);
        float wz1 = dz * ((unsigned)z1 < (unsigned)D_ ? 1.f : 0.f);
        float wy0 = (1.f - dy) * ((unsigned)y0 < (unsigned)H_ ? 1.f : 0.f);
        float wy1 = dy * ((unsigned)y1 < (unsigned)H_ ? 1.f : 0.f);
        float wx0 = (1.f - dx) * ((unsigned)x0 < (unsigned)W_ ? 1.f : 0.f);
        float wx1 = dx * ((unsigned)x1 < (unsigned)W_ ? 1.f : 0.f);
        int z0c = min(max(z0, 0), D_ - 1), z1c = min(max(z1, 0), D_ - 1);
        int y0c = min(max(y0, 0), H_ - 1), y1c = min(max(y1, 0), H_ - 1);
        int x0c = min(max(x0, 0), W_ - 1), x1c = min(max(x1, 0), W_ - 1);

        uint4 c0, c1, c2, c3, c4, c5, c6, c7;
        const bool inw = (y0c >= ylo) & (y1c <= yhi) & (x0c >= xlo) & (x1c <= xhi);
        if (inw) {
            const int ya = y0c - ylo, yb = y1c - ylo;
            const int xa = x0c - xlo, xb = x1c - xlo;
            const int r00 = (z0c * 10 + ya) * 28;
            const int r01 = (z0c * 10 + yb) * 28;
            const int r10 = (z1c * 10 + ya) * 28;
            const int r11 = (z1c * 10 + yb) * 28;
            c0 = lds_x[r00 + xa]; c1 = lds_x[r00 + xb];
            c2 = lds_x[r01 + xa]; c3 = lds_x[r01 + xb];
            c4 = lds_x[r10 + xa]; c5 = lds_x[r10 + xb];
            c6 = lds_x[r11 + xa]; c7 = lds_x[r11 + xb];
        } else {
            const int zy00 = z0c * HW_ + y0c * W_, zy01 = z0c * HW_ + y1c * W_;
            const int zy10 = z1c * HW_ + y0c * W_, zy11 = z1c * HW_ + y1c * W_;
            c0 = xs[zy00 + x0c]; c1 = xs[zy00 + x1c];
            c2 = xs[zy01 + x0c]; c3 = xs[zy01 + x1c];
            c4 = xs[zy10 + x0c]; c5 = xs[zy10 + x1c];
            c6 = xs[zy11 + x0c]; c7 = xs[zy11 + x1c];
        }

        U4H a0, a1;
        a0.u = make_uint4(0u, 0u, 0u, 0u);
        a1.u = make_uint4(0u, 0u, 0u, 0u);
        float wzy00 = wz0 * wy0, wzy01 = wz0 * wy1;
        float wzy10 = wz1 * wy0, wzy11 = wz1 * wy1;
        CORN(c0, wzy00 * wx0, a0); CORN(c1, wzy00 * wx1, a1);
        CORN(c2, wzy01 * wx0, a0); CORN(c3, wzy01 * wx1, a1);
        CORN(c4, wzy10 * wx0, a0); CORN(c5, wzy10 * wx1, a1);
        CORN(c6, wzy11 * wx0, a0); CORN(c7, wzy11 * wx1, a1);
        a0.h[0] = __hadd2(a0.h[0], a1.h[0]);
        a0.h[1] = __hadd2(a0.h[1], a1.h[1]);
        a0.h[2] = __hadd2(a0.h[2], a1.h[2]);
        a0.h[3] = __hadd2(a0.h[3], a1.h[3]);

        const size_t didx = ((size_t)(kv * NTILES_ + (n >> 4)) << 10) + g * 128 + (n & 15) * 8;
        *(uint4*)(val + didx) = a0.u;
    }
}

// Full-K GEMM: block = 1 n-tile, 4 waves split 27 taps (7/7/7/6), LDS-reduce.
__global__ __launch_bounds__(256, 4) void gemm_kernel(const __half* __restrict__ val,
                                                      const __half* __restrict__ wt2,
                                                      float* __restrict__ out) {
    __shared__ float red_s[4][64][20];
    const int tid = threadIdx.x, lane = tid & 63, wv = tid >> 6;
    const int nt = blockIdx.x;
    const int n0 = nt * NT_, nl = lane & 15;
    const int kv0 = wv * 7;
    f32x4 acc[4] = {};
    const __half* vb = val + (size_t)nt * 1024 + lane * 8;
    const __half* wb0 = wt2 + lane * 8;
#pragma unroll
    for (int t = 0; t < 7; ++t) {
        const int kv = kv0 + t;
        if (kv < KV_) {
            const __half* vp = vb + (size_t)kv * (NTILES_ * 1024);
            f16x8 bf0 = *(const f16x8*)(vp);
            f16x8 bf1 = *(const f16x8*)(vp + 512);
            const __half* wb = wb0 + (size_t)kv * 4096;
            f16x8 a00 = *(const f16x8*)(wb);
            f16x8 a01 = *(const f16x8*)(wb + 1024);
            f16x8 a02 = *(const f16x8*)(wb + 2048);
            f16x8 a03 = *(const f16x8*)(wb + 3072);
            f16x8 a10 = *(const f16x8*)(wb + 512);
            f16x8 a11 = *(const f16x8*)(wb + 1536);
            f16x8 a12 = *(const f16x8*)(wb + 2560);
            f16x8 a13 = *(const f16x8*)(wb + 3584);
            __builtin_amdgcn_s_setprio(1);
            acc[0] = __builtin_amdgcn_mfma_f32_16x16x32_f16(a00, bf0, acc[0], 0, 0, 0);
            acc[1] = __builtin_amdgcn_mfma_f32_16x16x32_f16(a01, bf0, acc[1], 0, 0, 0);
            acc[2] = __builtin_amdgcn_mfma_f32_16x16x32_f16(a02, bf0, acc[2], 0, 0, 0);
            acc[3] = __builtin_amdgcn_mfma_f32_16x16x32_f16(a03, bf0, acc[3], 0, 0, 0);
            acc[0] = __builtin_amdgcn_mfma_f32_16x16x32_f16(a10, bf1, acc[0], 0, 0, 0);
            acc[1] = __builtin_amdgcn_mfma_f32_16x16x32_f16(a11, bf1, acc[1], 0, 0, 0);
            acc[2] = __builtin_amdgcn_mfma_f32_16x16x32_f16(a12, bf1, acc[2], 0, 0, 0);
            acc[3] = __builtin_amdgcn_mfma_f32_16x16x32_f16(a13, bf1, acc[3], 0, 0, 0);
            __builtin_amdgcn_s_setprio(0);
        }
    }
#pragma unroll
    for (int of = 0; of < 4; ++of)
#pragma unroll
        for (int rr = 0; rr < 4; ++rr)
            red_s[wv][of * 16 + (lane >> 4) * 4 + rr][nl] = acc[of][rr];
    __syncthreads();
    const int o = tid >> 2, n4 = (tid & 3) * 4;
    f32x4 s = *(const f32x4*)&red_s[0][o][n4] + *(const f32x4*)&red_s[1][o][n4]
            + *(const f32x4*)&red_s[2][o][n4] + *(const f32x4*)&red_s[3][o][n4];
    *(f32x4*)(out + (size_t)o * N_ + n0 + n4) = s;
}

// ---------- fused fallback (R7, known-good) ----------
#define ISSUE(PH, KY, KX, OZ, OY, OX, BUF, WW) do {                            \
    float zc = (float)(zo + kz - 1) + (OZ);                                    \
    float yc = (float)(yo + (KY) - 1) + (OY);                                  \
    float xc = (float)(xo + (KX) - 1) + (OX);                                  \
    float zf = floorf(zc), yf = floorf(yc), xf = floorf(xc);                   \
    float dz = zc - zf, dy = yc - yf, dx = xc - xf;                            \
    int z0 = (int)zf, y0 = (int)yf, x0 = (int)xf;                              \
    int z1 = z0 + 1, y1 = y0 + 1, x1 = x0 + 1;                                 \
    WW[0] = (1.f - dz) * ((unsigned)z0 < (unsigned)D_ ? 1.f : 0.f);            \
    WW[1] = dz * ((unsigned)z1 < (unsigned)D_ ? 1.f : 0.f);                    \
    WW[2] = (1.f - dy) * ((unsigned)y0 < (unsigned)H_ ? 1.f : 0.f);            \
    WW[3] = dy * ((unsigned)y1 < (unsigned)H_ ? 1.f : 0.f);                    \
    WW[4] = (1.f - dx) * ((unsigned)x0 < (unsigned)W_ ? 1.f : 0.f);            \
    WW[5] = dx * ((unsigned)x1 < (unsigned)W_ ? 1.f : 0.f);                    \
    int z0c = min(max(z0, 0), D_ - 1), z1c = min(max(z1, 0), D_ - 1);          \
    int y0c = min(max(y0, 0), H_ - 1), y1c = min(max(y1, 0), H_ - 1);          \
    int x0c = min(max(x0, 0), W_ - 1), x1c = min(max(x1, 0), W_ - 1);          \
    const uint4* xp_ = xg[PH];                                                 \
    int zy00 = z0c * HW_ + y0c * W_, zy01 = z0c * HW_ + y1c * W_;              \
    int zy10 = z1c * HW_ + y0c * W_, zy11 = z1c * HW_ + y1c * W_;              \
    BUF[0] = xp_[zy00 + x0c]; BUF[1] = xp_[zy00 + x1c];                        \
    BUF[2] = xp_[zy01 + x0c]; BUF[3] = xp_[zy01 + x1c];                        \
    BUF[4] = xp_[zy10 + x0c]; BUF[5] = xp_[zy10 + x1c];                        \
    BUF[6] = xp_[zy11 + x0c]; BUF[7] = xp_[zy11 + x1c];                        \
} while (0)

#define CONSUME(BUF, WW, BF) do {                                              \
    U4H a0_, a1_;                                                              \
    a0_.u = make_uint4(0u, 0u, 0u, 0u);                                        \
    a1_.u = make_uint4(0u, 0u, 0u, 0u);                                        \
    float wzy00 = WW[0] * WW[2], wzy01 = WW[0] * WW[3];                        \
    float wzy10 = WW[1] * WW[2], wzy11 = WW[1] * WW[3];                        \
    CORN(BUF[0], wzy00 * WW[4], a0_); CORN(BUF[1], wzy00 * WW[5], a1_);        \
    CORN(BUF[2], wzy01 * WW[4], a0_); CORN(BUF[3], wzy01 * WW[5], a1_);        \
    CORN(BUF[4], wzy10 * WW[4], a0_); CORN(BUF[5], wzy10 * WW[5], a1_);        \
    CORN(BUF[6], wzy11 * WW[4], a0_); CORN(BUF[7], wzy11 * WW[5], a1_);        \
    a0_.h[0] = __hadd2(a0_.h[0], a1_.h[0]);                                    \
    a0_.h[1] = __hadd2(a0_.h[1], a1_.h[1]);                                    \
    a0_.h[2] = __hadd2(a0_.h[2], a1_.h[2]);                                    \
    a0_.h[3] = __hadd2(a0_.h[3], a1_.h[3]);                                    \
    BF = a0_.v;                                                                \
} while (0)

__global__ __launch_bounds__(192, 3) void dconv_kernel(const float* __restrict__ offset,
                                                       const __half* __restrict__ xt,
                                                       const __half* __restrict__ wt2,
                                                       float* __restrict__ out) {
    __shared__ float red_s[3][64][20];
    const int tid = threadIdx.x;
    const int lane = tid & 63;
    const int wv = tid >> 6;
    const int r = blockIdx.x;
    const int tile = (r & 7) * 196 + (r >> 3);
    const int n0 = tile * NT_;
    const int nl = lane & 15;
    const int n = n0 + nl;
    const int kv0 = wv * 9;
    const int kz = wv;

    const int zo = n / HW_;
    const int rem = n - zo * HW_;
    const int yo = rem / W_;
    const int xo = rem - yo * W_;
    const uint4* xg[2];
    const float* ob[2];
#pragma unroll
    for (int ph = 0; ph < 2; ++ph) {
        const int g = ph * 4 + (lane >> 4);
        xg[ph] = (const uint4*)(xt + (size_t)g * (N_ * 8));
        ob[ph] = offset + (size_t)g * (KV_ * 3 * N_) + n;
    }

    uint4 bufA[8], bufB[8];
    float wA[6], wB[6];
    f32x4 acc[4] = {};
    f16x8 bf0, bf1;

    float o0z[2], o0y[2], o0x[2], onz[2], ony[2], onx[2];
#pragma unroll
    for (int ph = 0; ph < 2; ++ph) {
        const float* p = ob[ph] + (size_t)kv0 * 3 * N_;
        o0z[ph] = __builtin_nontemporal_load(p);
        o0y[ph] = __builtin_nontemporal_load(p + N_);
        o0x[ph] = __builtin_nontemporal_load(p + 2 * N_);
    }
    ISSUE(0, 0, 0, o0z[0], o0y[0], o0x[0], bufA, wA);
    ISSUE(1, 0, 0, o0z[1], o0y[1], o0x[1], bufB, wB);
#pragma unroll
    for (int ph = 0; ph < 2; ++ph) {
        const float* p = ob[ph] + (size_t)(kv0 + 1) * 3 * N_;
        onz[ph] = __builtin_nontemporal_load(p);
        ony[ph] = __builtin_nontemporal_load(p + N_);
        onx[ph] = __builtin_nontemporal_load(p + 2 * N_);
    }

#pragma unroll
    for (int t = 0; t < 9; ++t) {
        const int kv = kv0 + t;
        const __half* wb = wt2 + (size_t)kv * 4096 + lane * 8;
        f16x8 af00 = *(const f16x8*)(wb);
        f16x8 af01 = *(const f16x8*)(wb + 1024);
        f16x8 af02 = *(const f16x8*)(wb + 2048);
        f16x8 af03 = *(const f16x8*)(wb + 3072);
        CONSUME(bufA, wA, bf0);
        if (t < 8)
            ISSUE(0, (t + 1) / 3, (t + 1) % 3, onz[0], ony[0], onx[0], bufA, wA);
        __builtin_amdgcn_s_setprio(1);
        acc[0] = __builtin_amdgcn_mfma_f32_16x16x32_f16(af00, bf0, acc[0], 0, 0, 0);
        acc[1] = __builtin_amdgcn_mfma_f32_16x16x32_f16(af01, bf0, acc[1], 0, 0, 0);
        acc[2] = __builtin_amdgcn_mfma_f32_16x16x32_f16(af02, bf0, acc[2], 0, 0, 0);
        acc[3] = __builtin_amdgcn_mfma_f32_16x16x32_f16(af03, bf0, acc[3], 0, 0, 0);
        __builtin_amdgcn_s_setprio(0);
        f16x8 af10 = *(const f16x8*)(wb + 512);
        f16x8 af11 = *(const f16x8*)(wb + 1536);
        f16x8 af12 = *(const f16x8*)(wb + 2560);
        f16x8 af13 = *(const f16x8*)(wb + 3584);
        CONSUME(bufB, wB, bf1);
        if (t < 8)
            ISSUE(1, (t + 1) / 3, (t + 1) % 3, onz[1], ony[1], onx[1], bufB, wB);
        float tnz[2], tny[2], tnx[2];
        if (t < 7) {
#pragma unroll
            for (int ph = 0; ph < 2; ++ph) {
                const float* p = ob[ph] + (size_t)(kv + 2) * 3 * N_;
                tnz[ph] = __builtin_nontemporal_load(p);
                tny[ph] = __builtin_nontemporal_load(p + N_);
                tnx[ph] = __builtin_nontemporal_load(p + 2 * N_);
            }
        }
        __builtin_amdgcn_s_setprio(1);
        acc[0] = __builtin_amdgcn_mfma_f32_16x16x32_f16(af10, bf1, acc[0], 0, 0, 0);
        acc[1] = __builtin_amdgcn_mfma_f32_16x16x32_f16(af11, bf1, acc[1], 0, 0, 0);
        acc[2] = __builtin_amdgcn_mfma_f32_16x16x32_f16(af12, bf1, acc[2], 0, 0, 0);
        acc[3] = __builtin_amdgcn_mfma_f32_16x16x32_f16(af13, bf1, acc[3], 0, 0, 0);
        __builtin_amdgcn_s_setprio(0);
        if (t < 7) {
#pragma unroll
            for (int ph = 0; ph < 2; ++ph) {
                onz[ph] = tnz[ph]; ony[ph] = tny[ph]; onx[ph] = tnx[ph];
            }
        }
    }

#pragma unroll
    for (int of = 0; of < 4; ++of)
#pragma unroll
        for (int rr = 0; rr < 4; ++rr)
            red_s[wv][of * 16 + (lane >> 4) * 4 + rr][nl] = acc[of][rr];
    __syncthreads();
    for (int e = tid; e < 256; e += 192) {
        const int o = e >> 2, n4 = (e & 3) * 4;
        f32x4 s = *(const f32x4*)&red_s[0][o][n4]
                + *(const f32x4*)&red_s[1][o][n4]
                + *(const f32x4*)&red_s[2][o][n4];
        *(f32x4*)(out + (size_t)o * N_ + n0 + n4) = s;
    }
}

extern "C" void kernel_launch(void* const* d_in, const int* in_sizes, int n_in,
                              void* d_out, int out_size, void* d_ws, size_t ws_size,
                              hipStream_t stream) {
    const float* x      = (const float*)d_in[0];
    const float* offset = (const float*)d_in[1];
    const float* weight = (const float*)d_in[2];
    float* out = (float*)d_out;

    __half* xt  = (__half*)d_ws;                 // 3,211,264 B
    __half* wt2 = xt + (size_t)8 * N_ * 8;       // 221,184 B
    const size_t base = 3432448;
    const size_t val_bytes = (size_t)KV_ * NTILES_ * 1024 * 2;  // 86,704,128 B

    prep_kernel<<<784 + 432, 256, 0, stream>>>(x, weight, xt, wt2);

    if (ws_size >= base + val_bytes) {
        __half* val = (__half*)((char*)d_ws + base);
        gather_kernel<<<2016, 512, 0, stream>>>(offset, xt, val);
        gemm_kernel<<<NTILES_, 256, 0, stream>>>(val, wt2, out);
    } else {
        dconv_kernel<<<NTILES_, 192, 0, stream>>>(offset, xt, wt2, out);
    }
}